// Round 7
// baseline (104.994 us; speedup 1.0000x reference)
//
#include <hip/hip_runtime.h>
#include <math.h>

// ShadowMapping forward: hard + soft shadow maps.
// R24 = R23 + nontemporal streams: out stores + depth/mask loads marked NT.
//   Post-mortem R23 (WIN −3.1us): cross-wave line reuse confirmed; fused
//   ~33us. Cost ledger: TA issue ~9us, L2 gather lines ~10us, VALU ~7us,
//   HBM writes ~5us — sum ~= measured => phases poorly overlapped, none at
//   its own ceiling. (OccupancyPercent metric shown unreliable: fill kernels
//   read 8% while saturating.)
//   R24 theory: write-allocating out stores (0.5MB/XCD/phase) + read-once
//   depth/mask lines (0.25MB/XCD) + 4MB dual-slice pressure at phase
//   boundaries evict the gather lines R23's reuse depends on. None of that
//   streamed data is re-read => nontemporal hint (MUBUF nt; coherence
//   unchanged) removes pollution at zero accuracy cost.
//   Rejected this round: persistent blocks (breaks R20 phase-fit: 16 slices
//   resident/XCD), wave reshape (null: ±50px depth-jitter dominates line
//   count), 1-tap cutoff raise (gain ~3-4us but pass/fail coin-flip —
//   reserve lever).
//   All per-(pixel,light) math bit-identical to R23.
//   Validated chain: geometry fmuladd (R2), plus-stencil blur (R6/R9),
//   poly-sin (R7), mask gating (R13), rowquad dwordx4 + phase A/B split +
//   sched_barrier (R18), XCD temporal phasing (R20), inline uniforms /
//   zero-ws (R22), 4x64 block cross-wave reuse (R23).

#define RESN 512
#define NL 16
#define NPIX (RESN*RESN)

typedef float f4a __attribute__((ext_vector_type(4), aligned(4)));

__global__ __launch_bounds__(256) void fused_kernel(
    const float* __restrict__ depth,
    const float* __restrict__ mask,
    const float* __restrict__ z_map,
    const float* __restrict__ als,
    float* __restrict__ out,
    float TANHF, float OZF, float OWF)
{
  #pragma clang fp contract(off)
  const float OFFS = -0.0642233295781f;
  const float CLB  = 0.4458709375254f;
  const float TWO_OVER_PI = 0.63661977236758134308f;
  // 8192 blocks: id>>10 = light pair (l, l+8) — contiguous 1024-block phase
  // spread over all 8 XCDs (load-balanced, R20). id&1023 = chunk:
  // chunk>>3 = 4-row group, chunk&7 = 64-col chunk. Thread: tid>>6 = row
  // within group (wave id), tid&63 = col within chunk. The 4 waves' gather
  // centers differ by <~3px => cross-wave L1/L2 line reuse. (validated R23)
  const int id = (int)blockIdx.x;
  const int l0 = id >> 10;
  const int chunk = id & 1023;
  const int row = ((chunk >> 3) << 2) + ((int)threadIdx.x >> 6);
  const int col = ((chunk & 7) << 6) + ((int)threadIdx.x & 63);
  const int p = (row << 9) + col;
  const int r = row, c = col;

  // ---- per-light uniforms, inline (ex-setup_kernel, bit-identical) ----
  float e00_[2], e02_[2], e10_[2], e11_[2], e12_[2];
  float e20_[2], e21_[2], e22_[2];
  float w0_[2], w1_[2], w0q_[2];
  bool  ft_[2];
  #pragma unroll
  for (int k = 0; k < 2; ++k) {
    const int l = l0 + (k << 3);
    float xd = als[l*7+0], yd = als[l*7+1], zd = als[l*7+2], sg = als[l*7+3];
    float cosp = sqrtf(xd*xd + zd*zd);
    float cost = zd / cosp;
    float sint = xd / cosp;
    e00_[k] = cost;
    e02_[k] = -sint;
    e10_[k] = (-sint)*yd;
    e11_[k] = cosp;
    e12_[k] = (-cost)*yd;
    e20_[k] = cosp*sint;
    e21_[k] = yd;
    e22_[k] = cosp*cost;
    // radius-1 Gaussian, normalized over the full 21-tap sum (validated R6)
    float sig = ((2.0f*(6.0f*sg + 1.0f)) - 1.0f) / 6.0f;
    float ivs = 1.0f/(sig*sig);
    float e1  = __builtin_amdgcn_exp2f(-0.72134752044448170368f*ivs);
    float e1sq = e1*e1;
    float e2  = e1sq*e1sq;
    float kinv = 1.0f/(1.0f + 2.0f*e1 + 2.0f*e2);
    float w1n = e1*kinv;
    w0_[k]  = kinv;
    w1_[k]  = w1n;
    // side-tap worst-case sf delta = (2/pi)*w0*4*w1n*0.93 <= 0.0115 at cutoff
    ft_[k]  = (w1n >= 0.0056f);          // 5-tap mode flag (validated R13)
    w0q_[k] = kinv*kinv;                 // w0^2 (1-tap path)
  }

  // read-once streams: NT loads (don't displace gather lines in L1/L2)
  float dz = __builtin_nontemporal_load(depth + p);
  float mk = __builtin_nontemporal_load(mask + p);
  float m1c = 2.0f * ((float)c / 512.0f + 0.0009765625f) - 1.0f;
  float m1r = 2.0f * ((float)r / 512.0f + 0.0009765625f) - 1.0f;
  float tT = dz * TANHF;
  float qx = tT * m1c;
  float qy = tT * m1r;
  float qz = 2.7f - dz;
  const bool live = (mk != 0.0f);

  float hard_out[2] = {0.0f, 0.0f};
  float soft_out[2] = {0.0f, 0.0f};

  if (live) {
    // ---- phase A: geometry + ALL gather issue for BOTH lights ----
    float rx[2], ry[2], rz[2], rw[2];   // row quad (covers u-1,u,u+1) or zg
    float zT[2], zB[2];
    float wvT_[2], wvB_[2];             // v-edge-masked side weights
    float dd_[2], dpo_[2];
    int   u_[2], ic_[2];

    #pragma unroll
    for (int k = 0; k < 2; ++k) {
      const int l = l0 + (k << 3);
      const int base = l << 18;

      // XLA dot emitter: sequential fmuladd over w (validated R2)
      float X1 = fmaf(qz, e02_[k], qx * e00_[k]);
      float Y1 = fmaf(qz, e12_[k], fmaf(qy, e11_[k], qx * e10_[k]));
      float T2 = fmaf(qz, e22_[k], fmaf(qy, e21_[k], qx * e20_[k]));
      float Z1 = T2 + (-2.7f);
      float ZZ = (Z1 * OZF) + OWF;
      float uf = (X1 + 1.0f) * 256.0f;
      float vf = (Y1 + 1.0f) * 256.0f;
      int u = (int)uf; u = u < 0 ? 0 : (u > 511 ? 511 : u);
      int v = (int)vf; v = v < 0 ? 0 : (v > 511 ? 511 : v);
      float dd = 0.5f * (1.0f + ZZ);
      dd = fminf(fmaxf(dd, 0.0f), 1.0f);
      dd_[k] = dd; dpo_[k] = dd + OFFS;
      u_[k] = u;

      const float* zrC = z_map + base + (v << 9);
      if (ft_[k]) {
        // one dwordx4 covers taps u-1,u,u+1; 8B-aligned base cuts
        // 64B-line straddle to 12.5%
        int b = (u - 1) & ~1;
        b = b < 0 ? 0 : (b > 508 ? 508 : b);
        f4a rv = *reinterpret_cast<const f4a*>(zrC + b);
        rx[k] = rv.x; ry[k] = rv.y; rz[k] = rv.z; rw[k] = rv.w;
        ic_[k] = u - b;                  // 0..3 (1 or 2 common case)
        int v0 = v > 0 ? v - 1 : 0;
        int v2 = v < 511 ? v + 1 : 511;
        zT[k] = z_map[base + (v0 << 9) + u];
        zB[k] = z_map[base + (v2 << 9) + u];
        wvT_[k] = (v > 0)   ? w1_[k] : 0.0f;
        wvB_[k] = (v < 511) ? w1_[k] : 0.0f;
      } else {
        ry[k] = zrC[u];                  // center only (1-tap mode)
        ic_[k] = 1;
        wvT_[k] = wvB_[k] = 0.0f;
      }
    }

    // Pin VMEM above the compute phase (ALU/SALU may cross to fill gaps).
    // mask 0x7 = ALU|VALU|SALU may cross; VMEM/DS may NOT.
    __builtin_amdgcn_sched_barrier(0x7);

    // ---- phase B: fval + blend for both lights ----
    #pragma unroll
    for (int k = 0; k < 2; ++k) {
      const float dpo = dpo_[k];
      // f = sum_{m odd<=7} (1/m) sin(m*pi*(z-dpo)) = s*P(s^2)
      auto fval = [&](float z) {
        float s = __builtin_amdgcn_sinf(0.5f * (z - dpo));   // revolutions
        float t = s * s;
        return s * fmaf(t, fmaf(t, fmaf(t, -9.142857142857142f, 19.2f),
                                -13.333333333333334f), 4.0f);
      };
      float w0 = w0_[k], w1 = w1_[k];
      float q, zg;
      if (ft_[k]) {
        // resolve edge-clamped row-quad indices (ic in {1,2} common case)
        bool e0 = ic_[k] == 0, e2 = ic_[k] == 2, e3 = ic_[k] == 3;
        float zC = e0 ? rx[k] : e2 ? rz[k] : e3 ? rw[k] : ry[k];
        float zL = e0 ? rx[k] : e2 ? ry[k] : e3 ? rz[k] : rx[k];
        float zR = e0 ? ry[k] : (e2 | e3) ? rw[k] : rz[k];
        int u = u_[k];
        float wuL = (u > 0)   ? w1 : 0.0f;
        float wuR = (u < 511) ? w1 : 0.0f;
        // same accumulation order as R17/R18/R20 (bit-compat): C, T, B, L, R
        float qs = w0 * fval(zC);
        qs = fmaf(wvT_[k], fval(zT[k]), qs);
        qs = fmaf(wvB_[k], fval(zB[k]), qs);
        qs = fmaf(wuL, fval(zL), qs);
        qs = fmaf(wuR, fval(zR), qs);
        q = TWO_OVER_PI * (w0 * qs);
        zg = zC;
      } else {
        // 1-tap mode: side weights < 5.6e-3 dropped (validated R13)
        zg = ry[k];
        q = TWO_OVER_PI * (w0q_[k] * fval(zg));
      }
      float diff = fmaxf(dd_[k] - zg, 0.0f);
      hard_out[k] = mk * ((diff > 0.008f) ? 0.0f : 1.0f);
      float qc = fminf(fmaxf(q, -CLB), CLB) / CLB;
      float sf = 0.5f * (qc + 1.0f);
      soft_out[k] = mk * fminf(fmaxf(sf, 0.0f), 1.0f);
    }
  }

  // write-once streams: NT stores (no L2 write-allocate pollution)
  #pragma unroll
  for (int k = 0; k < 2; ++k) {
    const int base = (l0 + (k << 3)) << 18;
    __builtin_nontemporal_store(hard_out[k], out + base + p);
    __builtin_nontemporal_store(soft_out[k], out + (NL*NPIX) + base + p);
  }
}

extern "C" void kernel_launch(void* const* d_in, const int* in_sizes, int n_in,
                              void* d_out, int out_size, void* d_ws, size_t ws_size,
                              hipStream_t stream) {
  (void)in_sizes; (void)n_in; (void)out_size; (void)d_ws; (void)ws_size;
  const float* depth = (const float*)d_in[0];
  const float* als   = (const float*)d_in[1];
  const float* mask  = (const float*)d_in[2];
  const float* z_map = (const float*)d_in[3];
  float* out = (float*)d_out;
  // constants in double, replicating numpy, then rounded to f32
  double TANH = tan(2.0*atan(0.5*36.0/50.0)/2.0);
  double NEARc = 2.7 - sqrt(2.0)*2.7*TANH;
  double FARc  = 2.7 + sqrt(2.0)*2.7*TANH;
  float ozf = (float)(-2.0/(FARc-NEARc));
  float owf = (float)((-(FARc+NEARc))/(FARc-NEARc));
  float tanhf_ = (float)TANH;

  fused_kernel<<<(NL/2)*NPIX/256, 256, 0, stream>>>(depth, mask, z_map, als,
                                                    out, tanhf_, ozf, owf);
}

// Round 8
// 97.804 us; speedup vs baseline: 1.0735x; 1.0735x over previous
//
#include <hip/hip_runtime.h>
#include <math.h>

// ShadowMapping forward: hard + soft shadow maps.
// R25 = exact R23 revert (session optimum, 98.1us).
//   Post-mortem R24 (REGRESSION +6.9us): nontemporal hints hurt on gfx950 —
//   NT stores demote L2 write-combining, and NT loads give up L1 residency
//   that cross-wave/cross-block reuse relies on (depth/mask rows are shared
//   by the 8 col-chunk blocks of a row group; I'd overlooked that). Stream
//   pollution theory refuted: 0.75MB/XCD of stream traffic vs 4MB L2 has
//   associativity headroom. LESSON: NT is not free; never NT lines another
//   wave may touch. Pure revert, no piggyback, for clean attribution.
//   Next-round levers (ranked): accuracy-budget 1-tap cutoff raise (reserve,
//   pass/fail risk), phase-B tree-sum chain shortening (breaks bit-compat,
//   test separately), else declare fused ~33us + harness floor ~55us.
//   Validated chain: geometry fmuladd (R2), plus-stencil blur (R6/R9),
//   poly-sin (R7), mask gating (R13), rowquad dwordx4 + phase A/B split +
//   sched_barrier (R18), XCD temporal phasing (R20), inline uniforms /
//   zero-ws (R22), 4x64 block cross-wave reuse (R23).

#define RESN 512
#define NL 16
#define NPIX (RESN*RESN)

typedef float f4a __attribute__((ext_vector_type(4), aligned(4)));

__global__ __launch_bounds__(256) void fused_kernel(
    const float* __restrict__ depth,
    const float* __restrict__ mask,
    const float* __restrict__ z_map,
    const float* __restrict__ als,
    float* __restrict__ out,
    float TANHF, float OZF, float OWF)
{
  #pragma clang fp contract(off)
  const float OFFS = -0.0642233295781f;
  const float CLB  = 0.4458709375254f;
  const float TWO_OVER_PI = 0.63661977236758134308f;
  // 8192 blocks: id>>10 = light pair (l, l+8) — contiguous 1024-block phase
  // spread over all 8 XCDs (load-balanced, R20). id&1023 = chunk:
  // chunk>>3 = 4-row group, chunk&7 = 64-col chunk. Thread: tid>>6 = row
  // within group (wave id), tid&63 = col within chunk. The 4 waves' gather
  // centers differ by <~3px => cross-wave L1/L2 line reuse. (validated R23)
  const int id = (int)blockIdx.x;
  const int l0 = id >> 10;
  const int chunk = id & 1023;
  const int row = ((chunk >> 3) << 2) + ((int)threadIdx.x >> 6);
  const int col = ((chunk & 7) << 6) + ((int)threadIdx.x & 63);
  const int p = (row << 9) + col;
  const int r = row, c = col;

  // ---- per-light uniforms, inline (ex-setup_kernel, bit-identical) ----
  float e00_[2], e02_[2], e10_[2], e11_[2], e12_[2];
  float e20_[2], e21_[2], e22_[2];
  float w0_[2], w1_[2], w0q_[2];
  bool  ft_[2];
  #pragma unroll
  for (int k = 0; k < 2; ++k) {
    const int l = l0 + (k << 3);
    float xd = als[l*7+0], yd = als[l*7+1], zd = als[l*7+2], sg = als[l*7+3];
    float cosp = sqrtf(xd*xd + zd*zd);
    float cost = zd / cosp;
    float sint = xd / cosp;
    e00_[k] = cost;
    e02_[k] = -sint;
    e10_[k] = (-sint)*yd;
    e11_[k] = cosp;
    e12_[k] = (-cost)*yd;
    e20_[k] = cosp*sint;
    e21_[k] = yd;
    e22_[k] = cosp*cost;
    // radius-1 Gaussian, normalized over the full 21-tap sum (validated R6)
    float sig = ((2.0f*(6.0f*sg + 1.0f)) - 1.0f) / 6.0f;
    float ivs = 1.0f/(sig*sig);
    float e1  = __builtin_amdgcn_exp2f(-0.72134752044448170368f*ivs);
    float e1sq = e1*e1;
    float e2  = e1sq*e1sq;
    float kinv = 1.0f/(1.0f + 2.0f*e1 + 2.0f*e2);
    float w1n = e1*kinv;
    w0_[k]  = kinv;
    w1_[k]  = w1n;
    // side-tap worst-case sf delta = (2/pi)*w0*4*w1n*0.93 <= 0.0115 at cutoff
    ft_[k]  = (w1n >= 0.0056f);          // 5-tap mode flag (validated R13)
    w0q_[k] = kinv*kinv;                 // w0^2 (1-tap path)
  }

  float dz = depth[p];
  float mk = mask[p];
  float m1c = 2.0f * ((float)c / 512.0f + 0.0009765625f) - 1.0f;
  float m1r = 2.0f * ((float)r / 512.0f + 0.0009765625f) - 1.0f;
  float tT = dz * TANHF;
  float qx = tT * m1c;
  float qy = tT * m1r;
  float qz = 2.7f - dz;
  const bool live = (mk != 0.0f);

  float hard_out[2] = {0.0f, 0.0f};
  float soft_out[2] = {0.0f, 0.0f};

  if (live) {
    // ---- phase A: geometry + ALL gather issue for BOTH lights ----
    float rx[2], ry[2], rz[2], rw[2];   // row quad (covers u-1,u,u+1) or zg
    float zT[2], zB[2];
    float wvT_[2], wvB_[2];             // v-edge-masked side weights
    float dd_[2], dpo_[2];
    int   u_[2], ic_[2];

    #pragma unroll
    for (int k = 0; k < 2; ++k) {
      const int l = l0 + (k << 3);
      const int base = l << 18;

      // XLA dot emitter: sequential fmuladd over w (validated R2)
      float X1 = fmaf(qz, e02_[k], qx * e00_[k]);
      float Y1 = fmaf(qz, e12_[k], fmaf(qy, e11_[k], qx * e10_[k]));
      float T2 = fmaf(qz, e22_[k], fmaf(qy, e21_[k], qx * e20_[k]));
      float Z1 = T2 + (-2.7f);
      float ZZ = (Z1 * OZF) + OWF;
      float uf = (X1 + 1.0f) * 256.0f;
      float vf = (Y1 + 1.0f) * 256.0f;
      int u = (int)uf; u = u < 0 ? 0 : (u > 511 ? 511 : u);
      int v = (int)vf; v = v < 0 ? 0 : (v > 511 ? 511 : v);
      float dd = 0.5f * (1.0f + ZZ);
      dd = fminf(fmaxf(dd, 0.0f), 1.0f);
      dd_[k] = dd; dpo_[k] = dd + OFFS;
      u_[k] = u;

      const float* zrC = z_map + base + (v << 9);
      if (ft_[k]) {
        // one dwordx4 covers taps u-1,u,u+1; 8B-aligned base cuts
        // 64B-line straddle to 12.5%
        int b = (u - 1) & ~1;
        b = b < 0 ? 0 : (b > 508 ? 508 : b);
        f4a rv = *reinterpret_cast<const f4a*>(zrC + b);
        rx[k] = rv.x; ry[k] = rv.y; rz[k] = rv.z; rw[k] = rv.w;
        ic_[k] = u - b;                  // 0..3 (1 or 2 common case)
        int v0 = v > 0 ? v - 1 : 0;
        int v2 = v < 511 ? v + 1 : 511;
        zT[k] = z_map[base + (v0 << 9) + u];
        zB[k] = z_map[base + (v2 << 9) + u];
        wvT_[k] = (v > 0)   ? w1_[k] : 0.0f;
        wvB_[k] = (v < 511) ? w1_[k] : 0.0f;
      } else {
        ry[k] = zrC[u];                  // center only (1-tap mode)
        ic_[k] = 1;
        wvT_[k] = wvB_[k] = 0.0f;
      }
    }

    // Pin VMEM above the compute phase (ALU/SALU may cross to fill gaps).
    // mask 0x7 = ALU|VALU|SALU may cross; VMEM/DS may NOT.
    __builtin_amdgcn_sched_barrier(0x7);

    // ---- phase B: fval + blend for both lights ----
    #pragma unroll
    for (int k = 0; k < 2; ++k) {
      const float dpo = dpo_[k];
      // f = sum_{m odd<=7} (1/m) sin(m*pi*(z-dpo)) = s*P(s^2)
      auto fval = [&](float z) {
        float s = __builtin_amdgcn_sinf(0.5f * (z - dpo));   // revolutions
        float t = s * s;
        return s * fmaf(t, fmaf(t, fmaf(t, -9.142857142857142f, 19.2f),
                                -13.333333333333334f), 4.0f);
      };
      float w0 = w0_[k], w1 = w1_[k];
      float q, zg;
      if (ft_[k]) {
        // resolve edge-clamped row-quad indices (ic in {1,2} common case)
        bool e0 = ic_[k] == 0, e2 = ic_[k] == 2, e3 = ic_[k] == 3;
        float zC = e0 ? rx[k] : e2 ? rz[k] : e3 ? rw[k] : ry[k];
        float zL = e0 ? rx[k] : e2 ? ry[k] : e3 ? rz[k] : rx[k];
        float zR = e0 ? ry[k] : (e2 | e3) ? rw[k] : rz[k];
        int u = u_[k];
        float wuL = (u > 0)   ? w1 : 0.0f;
        float wuR = (u < 511) ? w1 : 0.0f;
        // same accumulation order as R17/R18/R20 (bit-compat): C, T, B, L, R
        float qs = w0 * fval(zC);
        qs = fmaf(wvT_[k], fval(zT[k]), qs);
        qs = fmaf(wvB_[k], fval(zB[k]), qs);
        qs = fmaf(wuL, fval(zL), qs);
        qs = fmaf(wuR, fval(zR), qs);
        q = TWO_OVER_PI * (w0 * qs);
        zg = zC;
      } else {
        // 1-tap mode: side weights < 5.6e-3 dropped (validated R13)
        zg = ry[k];
        q = TWO_OVER_PI * (w0q_[k] * fval(zg));
      }
      float diff = fmaxf(dd_[k] - zg, 0.0f);
      hard_out[k] = mk * ((diff > 0.008f) ? 0.0f : 1.0f);
      float qc = fminf(fmaxf(q, -CLB), CLB) / CLB;
      float sf = 0.5f * (qc + 1.0f);
      soft_out[k] = mk * fminf(fmaxf(sf, 0.0f), 1.0f);
    }
  }

  #pragma unroll
  for (int k = 0; k < 2; ++k) {
    const int base = (l0 + (k << 3)) << 18;
    out[base + p] = hard_out[k];
    out[(NL*NPIX) + base + p] = soft_out[k];
  }
}

extern "C" void kernel_launch(void* const* d_in, const int* in_sizes, int n_in,
                              void* d_out, int out_size, void* d_ws, size_t ws_size,
                              hipStream_t stream) {
  (void)in_sizes; (void)n_in; (void)out_size; (void)d_ws; (void)ws_size;
  const float* depth = (const float*)d_in[0];
  const float* als   = (const float*)d_in[1];
  const float* mask  = (const float*)d_in[2];
  const float* z_map = (const float*)d_in[3];
  float* out = (float*)d_out;
  // constants in double, replicating numpy, then rounded to f32
  double TANH = tan(2.0*atan(0.5*36.0/50.0)/2.0);
  double NEARc = 2.7 - sqrt(2.0)*2.7*TANH;
  double FARc  = 2.7 + sqrt(2.0)*2.7*TANH;
  float ozf = (float)(-2.0/(FARc-NEARc));
  float owf = (float)((-(FARc+NEARc))/(FARc-NEARc));
  float tanhf_ = (float)TANH;

  fused_kernel<<<(NL/2)*NPIX/256, 256, 0, stream>>>(depth, mask, z_map, als,
                                                    out, tanhf_, ozf, owf);
}